// Round 8
// baseline (288.301 us; speedup 1.0000x reference)
//
#include <hip/hip_runtime.h>

typedef unsigned short u16;
typedef __attribute__((ext_vector_type(8))) short bf16x8;
typedef __attribute__((ext_vector_type(4))) float f32x4;

constexpr int CH = 64;      // IN_CH == HID == 64
constexpr int NG = 64;      // graphs
constexpr int NC = 10;      // classes
constexpr int SHIFT = 9;    // bucket = 512 nodes
constexpr int BW = 1 << SHIFT;
constexpr int EPW = 8192;   // edges per workgroup in bucket pass

__device__ __forceinline__ void f4add(float4& a, const float4 v) {
    a.x += v.x; a.y += v.y; a.z += v.z; a.w += v.w;
}
__device__ __forceinline__ u16 f2bf(float f) {   // RNE f32->bf16
    unsigned u = __float_as_uint(f);
    u = (u + 0x7FFFu + ((u >> 16) & 1u)) >> 16;
    return (u16)u;
}
__device__ __forceinline__ void bfacc(float4& a, unsigned lo, unsigned hi) {
    a.x += __uint_as_float(lo << 16);
    a.y += __uint_as_float(lo & 0xFFFF0000u);
    a.z += __uint_as_float(hi << 16);
    a.w += __uint_as_float(hi & 0xFFFF0000u);
}

// ---- B1: bin edges by dst bucket; packed record = src | (dstLocal<<17) ----
__global__ __launch_bounds__(256) void k_bucket(const int* __restrict__ src,
                                                const int* __restrict__ dst,
                                                int* __restrict__ bcnt,
                                                int* __restrict__ bbuf,
                                                int nb, int cap, int n_edges)
{
    __shared__ int hist[256];
    __shared__ int cur[256];
    int t = threadIdx.x;
    int e0 = blockIdx.x * EPW;
    int e1 = min(e0 + EPW, n_edges);
    if (t < nb) hist[t] = 0;
    __syncthreads();
    for (int e = e0 + t; e < e1; e += 256)
        atomicAdd(&hist[dst[e] >> SHIFT], 1);
    __syncthreads();
    if (t < nb) cur[t] = atomicAdd(&bcnt[t], hist[t]);   // reserve range
    __syncthreads();
    for (int e = e0 + t; e < e1; e += 256) {
        int d = dst[e];
        int b = d >> SHIFT;
        int pos = atomicAdd(&cur[b], 1);
        if (pos < cap)
            bbuf[(size_t)b * cap + pos] = src[e] | ((d & (BW - 1)) << 17);
    }
}

// ---- scan bucket counts -> bucket csr bases; also rowptr[n] ----------------
__global__ __launch_bounds__(256) void k_bscan(const int* __restrict__ bcnt,
                                               int* __restrict__ bbase,
                                               int* __restrict__ rowptr,
                                               int nb, int n, int cap)
{
    __shared__ int lds[256];
    int t = threadIdx.x;
    int v = (t < nb) ? min(bcnt[t], cap) : 0;
    lds[t] = v;
    __syncthreads();
    for (int off = 1; off < 256; off <<= 1) {
        int u = (t >= off) ? lds[t - off] : 0;
        __syncthreads();
        lds[t] += u;
        __syncthreads();
    }
    if (t < nb) bbase[t] = lds[t] - v;
    if (t == nb - 1) { bbase[nb] = lds[t]; rowptr[n] = lds[t]; }
}

// ---- B2: per-bucket local count + scan + place; contiguous csr window -----
__global__ __launch_bounds__(256) void k_build(const int* __restrict__ bbuf,
                                               const int* __restrict__ bcnt,
                                               const int* __restrict__ bbase,
                                               int* __restrict__ rowptr,
                                               int* __restrict__ csr,
                                               int cap, int n)
{
    __shared__ int hist[BW];
    __shared__ int cur[BW];
    __shared__ int psum[256];
    int b = blockIdx.x;
    int t = threadIdx.x;
    int cnt = min(bcnt[b], cap);
    int base = bbase[b];
    const int* mybuf = bbuf + (size_t)b * cap;
    hist[t] = 0; hist[t + 256] = 0;
    __syncthreads();
    for (int i = t; i < cnt; i += 256)
        atomicAdd(&hist[mybuf[i] >> 17], 1);
    __syncthreads();
    int h0 = hist[2 * t], h1 = hist[2 * t + 1];
    int ps = h0 + h1;
    psum[t] = ps;
    __syncthreads();
    for (int off = 1; off < 256; off <<= 1) {
        int u = (t >= off) ? psum[t - off] : 0;
        __syncthreads();
        psum[t] += u;
        __syncthreads();
    }
    int e0 = psum[t] - ps;                 // exclusive start of pair (2t,2t+1)
    int nodeBase = b * BW;
    cur[2 * t]     = base + e0;
    cur[2 * t + 1] = base + e0 + h0;
    if (nodeBase + 2 * t < n)     rowptr[nodeBase + 2 * t]     = base + e0;
    if (nodeBase + 2 * t + 1 < n) rowptr[nodeBase + 2 * t + 1] = base + e0 + h0;
    __syncthreads();
    for (int i = t; i < cnt; i += 256) {
        int v = mybuf[i];
        int pos = atomicAdd(&cur[v >> 17], 1);
        csr[pos] = v & 0x1FFFF;
    }
}

// -------- MFMA dense: Y = in@Wrel^T (bf16), R = in@Wroot^T + b (bf16) ------
// One wave per 16-node group (2 groups/wave). Consistent k-permutation on
// A and B frags cancels vs HW slot order. C/D: col=lane&15, row=(lane>>4)*4+reg.
template<bool BF16IN>
__global__ __launch_bounds__(256) void k_xform_mfma(const void* in_,
                                                    const float* __restrict__ Wrel,
                                                    const float* __restrict__ Wroot,
                                                    const float* __restrict__ bias,
                                                    u16* __restrict__ Y,
                                                    u16* R, int n, int ngroups)
{
    int lane = threadIdx.x & 63;
    int lr = lane & 15;      // A-row / B-row(=out ch) / D-col
    int g  = lane >> 4;      // k-group

    bf16x8 wf[2][4][2];
    const float* Wm[2] = { Wrel, Wroot };
#pragma unroll
    for (int m = 0; m < 2; ++m)
#pragma unroll
        for (int t = 0; t < 4; ++t)
#pragma unroll
            for (int kt = 0; kt < 2; ++kt) {
                const float* p = Wm[m] + (16 * t + lr) * CH + 32 * kt + 8 * g;
                bf16x8 v;
#pragma unroll
                for (int j = 0; j < 8; ++j) v[j] = (short)f2bf(p[j]);
                wf[m][t][kt] = v;
            }
    float bvt[4];
#pragma unroll
    for (int t = 0; t < 4; ++t) bvt[t] = bias[16 * t + lr];

    int wid = blockIdx.x * 4 + (threadIdx.x >> 6);
#pragma unroll
    for (int gi = 0; gi < 2; ++gi) {
        int grp = wid * 2 + gi;
        if (grp >= ngroups) return;
        int gbase = grp * 16;
        int arow = gbase + lr;
        if (arow >= n) arow = n - 1;

        bf16x8 af[2];
#pragma unroll
        for (int kt = 0; kt < 2; ++kt) {
            if (BF16IN) {
                const u16* hp = (const u16*)in_ + (size_t)arow * CH + kt * 32 + 8 * g;
                af[kt] = *(const bf16x8*)hp;
            } else {
                const float* xp = (const float*)in_ + (size_t)arow * CH + kt * 32 + 8 * g;
                bf16x8 v;
#pragma unroll
                for (int j = 0; j < 8; ++j) v[j] = (short)f2bf(xp[j]);
                af[kt] = v;
            }
        }

        f32x4 z = { 0.f, 0.f, 0.f, 0.f };
        f32x4 aY[4] = { z, z, z, z };
        f32x4 aR[4] = { z, z, z, z };
#pragma unroll
        for (int kt = 0; kt < 2; ++kt)
#pragma unroll
            for (int t = 0; t < 4; ++t) {
                aY[t] = __builtin_amdgcn_mfma_f32_16x16x32_bf16(af[kt], wf[0][t][kt], aY[t], 0, 0, 0);
                aR[t] = __builtin_amdgcn_mfma_f32_16x16x32_bf16(af[kt], wf[1][t][kt], aR[t], 0, 0, 0);
            }

#pragma unroll
        for (int t = 0; t < 4; ++t)
#pragma unroll
            for (int r = 0; r < 4; ++r) {
                int node = gbase + 4 * g + r;
                if (node < n) {
                    Y[(size_t)node * CH + 16 * t + lr] = f2bf(aY[t][r]);
                    R[(size_t)node * CH + 16 * t + lr] = f2bf(aR[t][r] + bvt[t]);
                }
            }
    }
}

// -------- gather v3: whole wave per node, 2 adjacent nodes interleaved ------
// 16 lanes per row (uint2 = 4 bf16 ch), 4 groups = 4 edges/row-load-instr,
// 16-edge main granule. Two nodes' main loops interleaved (wave-uniform
// branches) -> up to 8 row loads + 8 csr loads in flight. One-shot tail
// (<=15 edges) issues all loads before accumulating. Butterfly reduce leaves
// full sum in all lanes; store/atomic from grp==0 only.
template<bool POOL>
__global__ __launch_bounds__(256) void k_gather3(const u16* __restrict__ Y,
                                                 const int* __restrict__ rowptr,
                                                 const int* __restrict__ csr,
                                                 u16* RO,
                                                 const int* __restrict__ batch,
                                                 float* __restrict__ sums,
                                                 int n, int chunkPairs)
{
    int lane = threadIdx.x & 63;
    int grp = lane >> 4, sub = lane & 15;
    int wid = blockIdx.x * 4 + (threadIdx.x >> 6);
    int npairs = (n + 1) >> 1;
    int pb = wid * chunkPairs, pe = min(pb + chunkPairs, npairs);
    if (pb >= pe) return;
    float4 run = make_float4(0, 0, 0, 0);
    int gcur = -1;
    int eA0 = rowptr[2 * pb];
    for (int pair = pb; pair < pe; ++pair) {
        int nodeA = 2 * pair, nodeB = nodeA + 1;
        bool hasB = nodeB < n;
        int eA1 = rowptr[nodeA + 1];
        int eB1 = hasB ? rowptr[nodeB + 1] : eA1;
        uint2 prA = *(const uint2*)(RO + (size_t)nodeA * CH + sub * 4);
        uint2 prB = make_uint2(0, 0);
        if (hasB) prB = *(const uint2*)(RO + (size_t)nodeB * CH + sub * 4);

        float4 aA = make_float4(0, 0, 0, 0), bA = aA, aB = aA, bB = aA;
        int ea = eA0, eb = eA1;
        // ---- interleaved 16-edge main loops ----
        for (;;) {
            bool mA = (ea + 16 <= eA1);
            bool mB = (eb + 16 <= eB1);
            if (!mA && !mB) break;
            uint2 pa0, pa1, pa2, pa3, pb0, pb1, pb2, pb3;
            if (mA) {
                int s0 = csr[ea + grp],     s1 = csr[ea + 4 + grp];
                int s2 = csr[ea + 8 + grp], s3 = csr[ea + 12 + grp];
                pa0 = *(const uint2*)(Y + (size_t)s0 * CH + sub * 4);
                pa1 = *(const uint2*)(Y + (size_t)s1 * CH + sub * 4);
                pa2 = *(const uint2*)(Y + (size_t)s2 * CH + sub * 4);
                pa3 = *(const uint2*)(Y + (size_t)s3 * CH + sub * 4);
            }
            if (mB) {
                int s0 = csr[eb + grp],     s1 = csr[eb + 4 + grp];
                int s2 = csr[eb + 8 + grp], s3 = csr[eb + 12 + grp];
                pb0 = *(const uint2*)(Y + (size_t)s0 * CH + sub * 4);
                pb1 = *(const uint2*)(Y + (size_t)s1 * CH + sub * 4);
                pb2 = *(const uint2*)(Y + (size_t)s2 * CH + sub * 4);
                pb3 = *(const uint2*)(Y + (size_t)s3 * CH + sub * 4);
            }
            if (mA) {
                bfacc(aA, pa0.x, pa0.y); bfacc(bA, pa1.x, pa1.y);
                bfacc(aA, pa2.x, pa2.y); bfacc(bA, pa3.x, pa3.y);
                ea += 16;
            }
            if (mB) {
                bfacc(aB, pb0.x, pb0.y); bfacc(bB, pb1.x, pb1.y);
                bfacc(aB, pb2.x, pb2.y); bfacc(bB, pb3.x, pb3.y);
                eb += 16;
            }
        }
        // ---- one-shot tails (<=15 edges each): issue all loads, then acc ----
        {
            int rA = eA1 - ea, rB = eB1 - eb;
            bool fa0 = rA >= 4, fa1 = rA >= 8, fa2 = rA >= 12;
            bool fb0 = rB >= 4, fb1 = rB >= 8, fb2 = rB >= 12;
            int remA = ea + (rA & ~3), remB = eb + (rB & ~3);
            bool far = remA + grp < eA1, fbr = remB + grp < eB1;
            uint2 ta0, ta1, ta2, tar, tb0, tb1, tb2, tbr;
            if (fa0) { int s = csr[ea + grp];      ta0 = *(const uint2*)(Y + (size_t)s * CH + sub * 4); }
            if (fa1) { int s = csr[ea + 4 + grp];  ta1 = *(const uint2*)(Y + (size_t)s * CH + sub * 4); }
            if (fa2) { int s = csr[ea + 8 + grp];  ta2 = *(const uint2*)(Y + (size_t)s * CH + sub * 4); }
            if (far) { int s = csr[remA + grp];    tar = *(const uint2*)(Y + (size_t)s * CH + sub * 4); }
            if (fb0) { int s = csr[eb + grp];      tb0 = *(const uint2*)(Y + (size_t)s * CH + sub * 4); }
            if (fb1) { int s = csr[eb + 4 + grp];  tb1 = *(const uint2*)(Y + (size_t)s * CH + sub * 4); }
            if (fb2) { int s = csr[eb + 8 + grp];  tb2 = *(const uint2*)(Y + (size_t)s * CH + sub * 4); }
            if (fbr) { int s = csr[remB + grp];    tbr = *(const uint2*)(Y + (size_t)s * CH + sub * 4); }
            if (fa0) bfacc(aA, ta0.x, ta0.y);
            if (fa1) bfacc(bA, ta1.x, ta1.y);
            if (fa2) bfacc(aA, ta2.x, ta2.y);
            if (far) bfacc(bA, tar.x, tar.y);
            if (fb0) bfacc(aB, tb0.x, tb0.y);
            if (fb1) bfacc(bB, tb1.x, tb1.y);
            if (fb2) bfacc(aB, tb2.x, tb2.y);
            if (fbr) bfacc(bB, tbr.x, tbr.y);
        }
        eA0 = eB1;
        // ---- butterfly reduces (independent chains) ----
        f4add(aA, bA); f4add(aB, bB);
        aA.x += __shfl_xor(aA.x, 16); aB.x += __shfl_xor(aB.x, 16);
        aA.y += __shfl_xor(aA.y, 16); aB.y += __shfl_xor(aB.y, 16);
        aA.z += __shfl_xor(aA.z, 16); aB.z += __shfl_xor(aB.z, 16);
        aA.w += __shfl_xor(aA.w, 16); aB.w += __shfl_xor(aB.w, 16);
        aA.x += __shfl_xor(aA.x, 32); aB.x += __shfl_xor(aB.x, 32);
        aA.y += __shfl_xor(aA.y, 32); aB.y += __shfl_xor(aB.y, 32);
        aA.z += __shfl_xor(aA.z, 32); aB.z += __shfl_xor(aB.z, 32);
        aA.w += __shfl_xor(aA.w, 32); aB.w += __shfl_xor(aB.w, 32);

        float4 rf = make_float4(0, 0, 0, 0);
        bfacc(rf, prA.x, prA.y);
        float4 hA;
        hA.x = fmaxf(aA.x + rf.x, 0.f); hA.y = fmaxf(aA.y + rf.y, 0.f);
        hA.z = fmaxf(aA.z + rf.z, 0.f); hA.w = fmaxf(aA.w + rf.w, 0.f);
        float4 hB = make_float4(0, 0, 0, 0);
        if (hasB) {
            float4 rg = make_float4(0, 0, 0, 0);
            bfacc(rg, prB.x, prB.y);
            hB.x = fmaxf(aB.x + rg.x, 0.f); hB.y = fmaxf(aB.y + rg.y, 0.f);
            hB.z = fmaxf(aB.z + rg.z, 0.f); hB.w = fmaxf(aB.w + rg.w, 0.f);
        }
        if (!POOL) {
            if (grp == 0) {
                uint2 o;
                o.x = (unsigned)f2bf(hA.x) | ((unsigned)f2bf(hA.y) << 16);
                o.y = (unsigned)f2bf(hA.z) | ((unsigned)f2bf(hA.w) << 16);
                *(uint2*)(RO + (size_t)nodeA * CH + sub * 4) = o;
                if (hasB) {
                    uint2 p;
                    p.x = (unsigned)f2bf(hB.x) | ((unsigned)f2bf(hB.y) << 16);
                    p.y = (unsigned)f2bf(hB.z) | ((unsigned)f2bf(hB.w) << 16);
                    *(uint2*)(RO + (size_t)nodeB * CH + sub * 4) = p;
                }
            }
        } else {
            int gA = batch[nodeA];
            if (gA != gcur) {
                if (gcur >= 0 && grp == 0) {
                    float* s = sums + gcur * CH + sub * 4;
                    atomicAdd(s + 0, run.x); atomicAdd(s + 1, run.y);
                    atomicAdd(s + 2, run.z); atomicAdd(s + 3, run.w);
                }
                run = make_float4(0, 0, 0, 0);
                gcur = gA;
            }
            f4add(run, hA);
            if (hasB) {
                int gB = batch[nodeB];
                if (gB != gcur) {
                    if (grp == 0) {
                        float* s = sums + gcur * CH + sub * 4;
                        atomicAdd(s + 0, run.x); atomicAdd(s + 1, run.y);
                        atomicAdd(s + 2, run.z); atomicAdd(s + 3, run.w);
                    }
                    run = make_float4(0, 0, 0, 0);
                    gcur = gB;
                }
                f4add(run, hB);
            }
        }
    }
    if (POOL && gcur >= 0 && grp == 0) {
        float* s = sums + gcur * CH + sub * 4;
        atomicAdd(s + 0, run.x); atomicAdd(s + 1, run.y);
        atomicAdd(s + 2, run.z); atomicAdd(s + 3, run.w);
    }
}

// -------- final head --------------------------------------------------------
__global__ void k_final(const float* __restrict__ sums,
                        const int* __restrict__ batch,
                        const float* __restrict__ Wlin,
                        const float* __restrict__ blin,
                        float* __restrict__ out, int n_nodes)
{
    int t = threadIdx.x;
    if (t >= NG * NC) return;
    int g = t / NC, c = t % NC;
    int lo = 0, hi = n_nodes;
    while (lo < hi) { int mid = (lo + hi) >> 1; if (batch[mid] < g) lo = mid + 1; else hi = mid; }
    int lb = lo;
    lo = 0; hi = n_nodes;
    while (lo < hi) { int mid = (lo + hi) >> 1; if (batch[mid] < g + 1) lo = mid + 1; else hi = mid; }
    int cnt = lo - lb;
    float inv = 1.0f / fmaxf((float)cnt, 1.0f);
    float acc = blin[c];
    for (int k = 0; k < CH; ++k)
        acc += sums[g * CH + k] * inv * Wlin[c * CH + k];
    out[g * NC + c] = acc;
}

extern "C" void kernel_launch(void* const* d_in, const int* in_sizes, int n_in,
                              void* d_out, int out_size, void* d_ws, size_t ws_size,
                              hipStream_t stream)
{
    const float* x      = (const float*)d_in[0];
    const int*   ei     = (const int*)d_in[1];
    const int*   batch  = (const int*)d_in[2];
    const float* W1rel  = (const float*)d_in[3];
    const float* W1root = (const float*)d_in[4];
    const float* b1     = (const float*)d_in[5];
    const float* W2rel  = (const float*)d_in[6];
    const float* W2root = (const float*)d_in[7];
    const float* b2     = (const float*)d_in[8];
    const float* Wlin   = (const float*)d_in[9];
    const float* blin   = (const float*)d_in[10];
    float* out = (float*)d_out;

    int n_nodes = in_sizes[0] / CH;
    int n_edges = in_sizes[1] / 2;
    const int* src = ei;
    const int* dst = ei + n_edges;

    int nb  = (n_nodes + BW - 1) >> SHIFT;          // buckets (<=256)
    int cap = n_edges / nb + 2048;                  // per-bucket capacity

    // workspace: Ybf | Rbf(H) | rowptr | csr | bbuf | bcnt | bbase | sums (~40MB)
    u16*   Ybf    = (u16*)d_ws;
    u16*   Rbf    = Ybf + (size_t)n_nodes * CH;
    int*   rowptr = (int*)(Rbf + (size_t)n_nodes * CH);
    int*   csr    = rowptr + (n_nodes + 1);
    int*   bbuf   = csr + n_edges;
    int*   bcnt   = bbuf + (size_t)nb * cap;
    int*   bbase  = bcnt + 256;
    float* sums   = (float*)(bbase + 257);

    // ---- build CSR (dst -> srcs) via bucketed counting sort ----
    hipMemsetAsync(bcnt, 0, 256 * sizeof(int), stream);
    int b1blocks = (n_edges + EPW - 1) / EPW;
    k_bucket<<<b1blocks, 256, 0, stream>>>(src, dst, bcnt, bbuf, nb, cap, n_edges);
    k_bscan<<<1, 256, 0, stream>>>(bcnt, bbase, rowptr, nb, n_nodes, cap);
    k_build<<<nb, 256, 0, stream>>>(bbuf, bcnt, bbase, rowptr, csr, cap, n_nodes);

    int ngroups16 = (n_nodes + 15) / 16;
    int xblocks = (ngroups16 + 7) / 8;              // 4 waves x 2 groups

    int waves = 2048 * 4;
    int npairs = (n_nodes + 1) / 2;
    int chunkPairs = (npairs + waves - 1) / waves;

    // ---- layer 1 ----
    k_xform_mfma<false><<<xblocks, 256, 0, stream>>>(x, W1rel, W1root, b1,
                                                     Ybf, Rbf, n_nodes, ngroups16);
    k_gather3<false><<<2048, 256, 0, stream>>>(Ybf, rowptr, csr, Rbf,
                                               batch, sums, n_nodes, chunkPairs);

    // ---- layer 2 ----
    k_xform_mfma<true><<<xblocks, 256, 0, stream>>>(Rbf, W2rel, W2root, b2,
                                                    Ybf, Rbf, n_nodes, ngroups16);
    hipMemsetAsync(sums, 0, NG * CH * sizeof(float), stream);
    k_gather3<true><<<2048, 256, 0, stream>>>(Ybf, rowptr, csr, Rbf,
                                              batch, sums, n_nodes, chunkPairs);

    // ---- head ----
    k_final<<<1, NG * NC, 0, stream>>>(sums, batch, Wlin, blin, out, n_nodes);
}

// Round 9
// 261.183 us; speedup vs baseline: 1.1038x; 1.1038x over previous
//
#include <hip/hip_runtime.h>

typedef unsigned short u16;
typedef __attribute__((ext_vector_type(8))) short bf16x8;
typedef __attribute__((ext_vector_type(4))) float f32x4;

constexpr int CH = 64;      // IN_CH == HID == 64
constexpr int NG = 64;      // graphs
constexpr int NC = 10;      // classes
constexpr int SHIFT = 9;    // bucket = 512 nodes
constexpr int BW = 1 << SHIFT;
constexpr int EPW = 8192;   // edges per workgroup in bucket pass

__device__ __forceinline__ void f4add(float4& a, const float4 v) {
    a.x += v.x; a.y += v.y; a.z += v.z; a.w += v.w;
}
__device__ __forceinline__ u16 f2bf(float f) {   // RNE f32->bf16
    unsigned u = __float_as_uint(f);
    u = (u + 0x7FFFu + ((u >> 16) & 1u)) >> 16;
    return (u16)u;
}
__device__ __forceinline__ void bfacc(float4& a, unsigned lo, unsigned hi) {
    a.x += __uint_as_float(lo << 16);
    a.y += __uint_as_float(lo & 0xFFFF0000u);
    a.z += __uint_as_float(hi << 16);
    a.w += __uint_as_float(hi & 0xFFFF0000u);
}
__device__ __forceinline__ int pick4(int4 v, int g) {   // v[g], branch-free
    int t0 = (g & 1) ? v.y : v.x;
    int t1 = (g & 1) ? v.w : v.z;
    return (g & 2) ? t1 : t0;
}

// ---- B1: bin edges by dst bucket; packed record = src | (dstLocal<<17) ----
__global__ __launch_bounds__(256) void k_bucket(const int* __restrict__ src,
                                                const int* __restrict__ dst,
                                                int* __restrict__ bcnt,
                                                int* __restrict__ bbuf,
                                                int nb, int cap, int n_edges)
{
    __shared__ int hist[256];
    __shared__ int cur[256];
    int t = threadIdx.x;
    int e0 = blockIdx.x * EPW;
    int e1 = min(e0 + EPW, n_edges);
    if (t < nb) hist[t] = 0;
    __syncthreads();
    for (int e = e0 + t; e < e1; e += 256)
        atomicAdd(&hist[dst[e] >> SHIFT], 1);
    __syncthreads();
    if (t < nb) cur[t] = atomicAdd(&bcnt[t], hist[t]);   // reserve range
    __syncthreads();
    for (int e = e0 + t; e < e1; e += 256) {
        int d = dst[e];
        int b = d >> SHIFT;
        int pos = atomicAdd(&cur[b], 1);
        if (pos < cap)
            bbuf[(size_t)b * cap + pos] = src[e] | ((d & (BW - 1)) << 17);
    }
}

// ---- scan bucket counts -> bucket csr bases; also rowptr[n] ----------------
__global__ __launch_bounds__(256) void k_bscan(const int* __restrict__ bcnt,
                                               int* __restrict__ bbase,
                                               int* __restrict__ rowptr,
                                               int nb, int n, int cap)
{
    __shared__ int lds[256];
    int t = threadIdx.x;
    int v = (t < nb) ? min(bcnt[t], cap) : 0;
    lds[t] = v;
    __syncthreads();
    for (int off = 1; off < 256; off <<= 1) {
        int u = (t >= off) ? lds[t - off] : 0;
        __syncthreads();
        lds[t] += u;
        __syncthreads();
    }
    if (t < nb) bbase[t] = lds[t] - v;
    if (t == nb - 1) { bbase[nb] = lds[t]; rowptr[n] = lds[t]; }
}

// ---- B2: per-bucket local count + scan + place; contiguous csr window -----
__global__ __launch_bounds__(256) void k_build(const int* __restrict__ bbuf,
                                               const int* __restrict__ bcnt,
                                               const int* __restrict__ bbase,
                                               int* __restrict__ rowptr,
                                               int* __restrict__ csr,
                                               int cap, int n)
{
    __shared__ int hist[BW];
    __shared__ int cur[BW];
    __shared__ int psum[256];
    int b = blockIdx.x;
    int t = threadIdx.x;
    int cnt = min(bcnt[b], cap);
    int base = bbase[b];
    const int* mybuf = bbuf + (size_t)b * cap;
    hist[t] = 0; hist[t + 256] = 0;
    __syncthreads();
    for (int i = t; i < cnt; i += 256)
        atomicAdd(&hist[mybuf[i] >> 17], 1);
    __syncthreads();
    int h0 = hist[2 * t], h1 = hist[2 * t + 1];
    int ps = h0 + h1;
    psum[t] = ps;
    __syncthreads();
    for (int off = 1; off < 256; off <<= 1) {
        int u = (t >= off) ? psum[t - off] : 0;
        __syncthreads();
        psum[t] += u;
        __syncthreads();
    }
    int e0 = psum[t] - ps;                 // exclusive start of pair (2t,2t+1)
    int nodeBase = b * BW;
    cur[2 * t]     = base + e0;
    cur[2 * t + 1] = base + e0 + h0;
    if (nodeBase + 2 * t < n)     rowptr[nodeBase + 2 * t]     = base + e0;
    if (nodeBase + 2 * t + 1 < n) rowptr[nodeBase + 2 * t + 1] = base + e0 + h0;
    __syncthreads();
    for (int i = t; i < cnt; i += 256) {
        int v = mybuf[i];
        int pos = atomicAdd(&cur[v >> 17], 1);
        csr[pos] = v & 0x1FFFF;
    }
}

// -------- MFMA dense: Y = in@Wrel^T (bf16), R = in@Wroot^T + b (bf16) ------
// One wave per 16-node group (2 groups/wave). Consistent k-permutation on
// A and B frags cancels vs HW slot order. C/D: col=lane&15, row=(lane>>4)*4+reg.
// Block 0 also zeroes Y row n (the gather's dummy row).
template<bool BF16IN>
__global__ __launch_bounds__(256) void k_xform_mfma(const void* in_,
                                                    const float* __restrict__ Wrel,
                                                    const float* __restrict__ Wroot,
                                                    const float* __restrict__ bias,
                                                    u16* __restrict__ Y,
                                                    u16* R, int n, int ngroups)
{
    if (blockIdx.x == 0 && threadIdx.x < 64)
        Y[(size_t)n * CH + threadIdx.x] = 0;     // zero dummy row

    int lane = threadIdx.x & 63;
    int lr = lane & 15;      // A-row / B-row(=out ch) / D-col
    int g  = lane >> 4;      // k-group

    bf16x8 wf[2][4][2];
    const float* Wm[2] = { Wrel, Wroot };
#pragma unroll
    for (int m = 0; m < 2; ++m)
#pragma unroll
        for (int t = 0; t < 4; ++t)
#pragma unroll
            for (int kt = 0; kt < 2; ++kt) {
                const float* p = Wm[m] + (16 * t + lr) * CH + 32 * kt + 8 * g;
                bf16x8 v;
#pragma unroll
                for (int j = 0; j < 8; ++j) v[j] = (short)f2bf(p[j]);
                wf[m][t][kt] = v;
            }
    float bvt[4];
#pragma unroll
    for (int t = 0; t < 4; ++t) bvt[t] = bias[16 * t + lr];

    int wid = blockIdx.x * 4 + (threadIdx.x >> 6);
#pragma unroll
    for (int gi = 0; gi < 2; ++gi) {
        int grp = wid * 2 + gi;
        if (grp >= ngroups) return;
        int gbase = grp * 16;
        int arow = gbase + lr;
        if (arow >= n) arow = n - 1;

        bf16x8 af[2];
#pragma unroll
        for (int kt = 0; kt < 2; ++kt) {
            if (BF16IN) {
                const u16* hp = (const u16*)in_ + (size_t)arow * CH + kt * 32 + 8 * g;
                af[kt] = *(const bf16x8*)hp;
            } else {
                const float* xp = (const float*)in_ + (size_t)arow * CH + kt * 32 + 8 * g;
                bf16x8 v;
#pragma unroll
                for (int j = 0; j < 8; ++j) v[j] = (short)f2bf(xp[j]);
                af[kt] = v;
            }
        }

        f32x4 z = { 0.f, 0.f, 0.f, 0.f };
        f32x4 aY[4] = { z, z, z, z };
        f32x4 aR[4] = { z, z, z, z };
#pragma unroll
        for (int kt = 0; kt < 2; ++kt)
#pragma unroll
            for (int t = 0; t < 4; ++t) {
                aY[t] = __builtin_amdgcn_mfma_f32_16x16x32_bf16(af[kt], wf[0][t][kt], aY[t], 0, 0, 0);
                aR[t] = __builtin_amdgcn_mfma_f32_16x16x32_bf16(af[kt], wf[1][t][kt], aR[t], 0, 0, 0);
            }

#pragma unroll
        for (int t = 0; t < 4; ++t)
#pragma unroll
            for (int r = 0; r < 4; ++r) {
                int node = gbase + 4 * g + r;
                if (node < n) {
                    Y[(size_t)node * CH + 16 * t + lr] = f2bf(aY[t][r]);
                    R[(size_t)node * CH + 16 * t + lr] = f2bf(aR[t][r] + bvt[t]);
                }
            }
    }
}

// -------- gather v4: R5 skeleton + branch-free 16-slot granule --------------
// Whole wave per node; 16 lanes x uint2 = full bf16 row; 4 groups x 4 quads.
// csr read as 4 wave-uniform int4 loads; invalid slots select the zero row n
// (v_cndmask, no divergence) -> every deg<=16 node is ONE vmcnt round trip.
// RO row prefetched before the edge loop.
template<bool POOL>
__global__ __launch_bounds__(256) void k_gather4(const u16* __restrict__ Y,
                                                 const int* __restrict__ rowptr,
                                                 const int* __restrict__ csr,
                                                 u16* RO,
                                                 const int* __restrict__ batch,
                                                 float* __restrict__ sums,
                                                 int n, int chunk)
{
    int lane = threadIdx.x & 63;
    int grp = lane >> 4, sub = lane & 15;
    int wid = blockIdx.x * 4 + (threadIdx.x >> 6);
    int nw = gridDim.x * 4;
    int nb, ne, step;
    if (POOL) { nb = wid * chunk; ne = min(nb + chunk, n); step = 1; }
    else      { nb = wid; ne = n; step = nw; }
    if (nb >= n) return;
    float4 run = make_float4(0, 0, 0, 0);
    int gcur = -1;
    for (int node = nb; node < ne; node += step) {
        int e0 = rowptr[node], e1 = rowptr[node + 1];
        uint2 pr = *(const uint2*)(RO + (size_t)node * CH + sub * 4);
        float4 a0 = make_float4(0, 0, 0, 0), a1 = a0;
        for (int e = e0; e < e1; e += 16) {
            int4 i0 = *(const int4*)(csr + e);
            int4 i1 = *(const int4*)(csr + e + 4);
            int4 i2 = *(const int4*)(csr + e + 8);
            int4 i3 = *(const int4*)(csr + e + 12);
            int s0 = (e + grp      < e1) ? pick4(i0, grp) : n;
            int s1 = (e + 4 + grp  < e1) ? pick4(i1, grp) : n;
            int s2 = (e + 8 + grp  < e1) ? pick4(i2, grp) : n;
            int s3 = (e + 12 + grp < e1) ? pick4(i3, grp) : n;
            uint2 p0 = *(const uint2*)(Y + (size_t)s0 * CH + sub * 4);
            uint2 p1 = *(const uint2*)(Y + (size_t)s1 * CH + sub * 4);
            uint2 p2 = *(const uint2*)(Y + (size_t)s2 * CH + sub * 4);
            uint2 p3 = *(const uint2*)(Y + (size_t)s3 * CH + sub * 4);
            bfacc(a0, p0.x, p0.y); bfacc(a1, p1.x, p1.y);
            bfacc(a0, p2.x, p2.y); bfacc(a1, p3.x, p3.y);
        }
        f4add(a0, a1);
        a0.x += __shfl_xor(a0.x, 16); a0.y += __shfl_xor(a0.y, 16);
        a0.z += __shfl_xor(a0.z, 16); a0.w += __shfl_xor(a0.w, 16);
        a0.x += __shfl_xor(a0.x, 32); a0.y += __shfl_xor(a0.y, 32);
        a0.z += __shfl_xor(a0.z, 32); a0.w += __shfl_xor(a0.w, 32);
        float4 r = make_float4(0, 0, 0, 0);
        bfacc(r, pr.x, pr.y);
        float4 h;
        h.x = fmaxf(a0.x + r.x, 0.f); h.y = fmaxf(a0.y + r.y, 0.f);
        h.z = fmaxf(a0.z + r.z, 0.f); h.w = fmaxf(a0.w + r.w, 0.f);
        if (!POOL) {
            if (grp == 0) {
                uint2 o;
                o.x = (unsigned)f2bf(h.x) | ((unsigned)f2bf(h.y) << 16);
                o.y = (unsigned)f2bf(h.z) | ((unsigned)f2bf(h.w) << 16);
                *(uint2*)(RO + (size_t)node * CH + sub * 4) = o;
            }
        } else {
            int g = batch[node];
            if (g != gcur) {
                if (gcur >= 0 && grp == 0) {
                    float* s = sums + gcur * CH + sub * 4;
                    atomicAdd(s + 0, run.x); atomicAdd(s + 1, run.y);
                    atomicAdd(s + 2, run.z); atomicAdd(s + 3, run.w);
                }
                run = make_float4(0, 0, 0, 0);
                gcur = g;
            }
            f4add(run, h);
        }
    }
    if (POOL && gcur >= 0 && grp == 0) {
        float* s = sums + gcur * CH + sub * 4;
        atomicAdd(s + 0, run.x); atomicAdd(s + 1, run.y);
        atomicAdd(s + 2, run.z); atomicAdd(s + 3, run.w);
    }
}

// -------- final head --------------------------------------------------------
__global__ void k_final(const float* __restrict__ sums,
                        const int* __restrict__ batch,
                        const float* __restrict__ Wlin,
                        const float* __restrict__ blin,
                        float* __restrict__ out, int n_nodes)
{
    int t = threadIdx.x;
    if (t >= NG * NC) return;
    int g = t / NC, c = t % NC;
    int lo = 0, hi = n_nodes;
    while (lo < hi) { int mid = (lo + hi) >> 1; if (batch[mid] < g) lo = mid + 1; else hi = mid; }
    int lb = lo;
    lo = 0; hi = n_nodes;
    while (lo < hi) { int mid = (lo + hi) >> 1; if (batch[mid] < g + 1) lo = mid + 1; else hi = mid; }
    int cnt = lo - lb;
    float inv = 1.0f / fmaxf((float)cnt, 1.0f);
    float acc = blin[c];
    for (int k = 0; k < CH; ++k)
        acc += sums[g * CH + k] * inv * Wlin[c * CH + k];
    out[g * NC + c] = acc;
}

extern "C" void kernel_launch(void* const* d_in, const int* in_sizes, int n_in,
                              void* d_out, int out_size, void* d_ws, size_t ws_size,
                              hipStream_t stream)
{
    const float* x      = (const float*)d_in[0];
    const int*   ei     = (const int*)d_in[1];
    const int*   batch  = (const int*)d_in[2];
    const float* W1rel  = (const float*)d_in[3];
    const float* W1root = (const float*)d_in[4];
    const float* b1     = (const float*)d_in[5];
    const float* W2rel  = (const float*)d_in[6];
    const float* W2root = (const float*)d_in[7];
    const float* b2     = (const float*)d_in[8];
    const float* Wlin   = (const float*)d_in[9];
    const float* blin   = (const float*)d_in[10];
    float* out = (float*)d_out;

    int n_nodes = in_sizes[0] / CH;
    int n_edges = in_sizes[1] / 2;
    const int* src = ei;
    const int* dst = ei + n_edges;

    int nb  = (n_nodes + BW - 1) >> SHIFT;          // buckets (<=256)
    int cap = n_edges / nb + 2048;                  // per-bucket capacity

    // workspace: Ybf(n+1 rows) | Rbf | rowptr | csr(+16 pad) | bbuf | bcnt | bbase | sums
    u16*   Ybf    = (u16*)d_ws;
    u16*   Rbf    = Ybf + (size_t)(n_nodes + 1) * CH;
    int*   rowptr = (int*)(Rbf + (size_t)n_nodes * CH);
    int*   csr    = rowptr + (n_nodes + 1);
    int*   bbuf   = csr + n_edges + 16;             // +16: int4 overread pad
    int*   bcnt   = bbuf + (size_t)nb * cap;
    int*   bbase  = bcnt + 256;
    float* sums   = (float*)(bbase + 257);

    // ---- build CSR (dst -> srcs) via bucketed counting sort ----
    hipMemsetAsync(bcnt, 0, 256 * sizeof(int), stream);
    int b1blocks = (n_edges + EPW - 1) / EPW;
    k_bucket<<<b1blocks, 256, 0, stream>>>(src, dst, bcnt, bbuf, nb, cap, n_edges);
    k_bscan<<<1, 256, 0, stream>>>(bcnt, bbase, rowptr, nb, n_nodes, cap);
    k_build<<<nb, 256, 0, stream>>>(bbuf, bcnt, bbase, rowptr, csr, cap, n_nodes);

    int ngroups16 = (n_nodes + 15) / 16;
    int xblocks = (ngroups16 + 7) / 8;              // 4 waves x 2 groups

    int waves = 2048 * 4;
    int chunk = (n_nodes + waves - 1) / waves;

    // ---- layer 1 ----
    k_xform_mfma<false><<<xblocks, 256, 0, stream>>>(x, W1rel, W1root, b1,
                                                     Ybf, Rbf, n_nodes, ngroups16);
    k_gather4<false><<<2048, 256, 0, stream>>>(Ybf, rowptr, csr, Rbf,
                                               batch, sums, n_nodes, chunk);

    // ---- layer 2 ----
    k_xform_mfma<true><<<xblocks, 256, 0, stream>>>(Rbf, W2rel, W2root, b2,
                                                    Ybf, Rbf, n_nodes, ngroups16);
    hipMemsetAsync(sums, 0, NG * CH * sizeof(float), stream);
    k_gather4<true><<<2048, 256, 0, stream>>>(Ybf, rowptr, csr, Rbf,
                                              batch, sums, n_nodes, chunk);

    // ---- head ----
    k_final<<<1, NG * NC, 0, stream>>>(sums, batch, Wlin, blin, out, n_nodes);
}

// Round 11
// 228.250 us; speedup vs baseline: 1.2631x; 1.1443x over previous
//
#include <hip/hip_runtime.h>

typedef unsigned short u16;
typedef __attribute__((ext_vector_type(8))) short bf16x8;
typedef __attribute__((ext_vector_type(4))) float f32x4;

constexpr int CH = 64;      // IN_CH == HID == 64
constexpr int NG = 64;      // graphs
constexpr int NC = 10;      // classes
constexpr int SHIFT = 9;    // bucket = 512 nodes
constexpr int BW = 1 << SHIFT;
constexpr int EPW = 8192;   // edges per workgroup in bucket pass

__device__ __forceinline__ void f4add(float4& a, const float4 v) {
    a.x += v.x; a.y += v.y; a.z += v.z; a.w += v.w;
}
__device__ __forceinline__ u16 f2bf(float f) {   // RNE f32->bf16
    unsigned u = __float_as_uint(f);
    u = (u + 0x7FFFu + ((u >> 16) & 1u)) >> 16;
    return (u16)u;
}
__device__ __forceinline__ void bfacc(float4& a, unsigned lo, unsigned hi) {
    a.x += __uint_as_float(lo << 16);
    a.y += __uint_as_float(lo & 0xFFFF0000u);
    a.z += __uint_as_float(hi << 16);
    a.w += __uint_as_float(hi & 0xFFFF0000u);
}

// ---- B1: bin edges by dst bucket; packed record = src | (dstLocal<<17) ----
__global__ __launch_bounds__(256) void k_bucket(const int* __restrict__ src,
                                                const int* __restrict__ dst,
                                                int* __restrict__ bcnt,
                                                int* __restrict__ bbuf,
                                                int nb, int cap, int n_edges)
{
    __shared__ int hist[256];
    __shared__ int cur[256];
    int t = threadIdx.x;
    int e0 = blockIdx.x * EPW;
    int e1 = min(e0 + EPW, n_edges);
    if (t < nb) hist[t] = 0;
    __syncthreads();
    for (int e = e0 + t; e < e1; e += 256)
        atomicAdd(&hist[dst[e] >> SHIFT], 1);
    __syncthreads();
    if (t < nb) cur[t] = atomicAdd(&bcnt[t], hist[t]);   // reserve range
    __syncthreads();
    for (int e = e0 + t; e < e1; e += 256) {
        int d = dst[e];
        int b = d >> SHIFT;
        int pos = atomicAdd(&cur[b], 1);
        if (pos < cap)
            bbuf[(size_t)b * cap + pos] = src[e] | ((d & (BW - 1)) << 17);
    }
}

// ---- B2: fused bucket-scan + per-bucket count/scan/place -------------------
// Each block redundantly scans the (<=256) bucket counts in LDS to get its
// own csr base (removes the separate k_bscan dispatch); block 0 writes
// rowptr[n]. Then local 512-node histogram + scan + place as before.
__global__ __launch_bounds__(256) void k_build(const int* __restrict__ bbuf,
                                               const int* __restrict__ bcnt,
                                               int* __restrict__ rowptr,
                                               int* __restrict__ csr,
                                               int nb, int cap, int n)
{
    __shared__ int sc[256];
    __shared__ int hist[BW];
    __shared__ int cur[BW];
    __shared__ int psum[256];
    int b = blockIdx.x;
    int t = threadIdx.x;
    // ---- bucket-level exclusive scan (redundant per block) ----
    int v = (t < nb) ? min(bcnt[t], cap) : 0;
    sc[t] = v;
    __syncthreads();
    for (int off = 1; off < 256; off <<= 1) {
        int u = (t >= off) ? sc[t - off] : 0;
        __syncthreads();
        sc[t] += u;
        __syncthreads();
    }
    if (b == 0 && t == nb - 1) rowptr[n] = sc[t];   // grand total
    int cnt = min(bcnt[b], cap);
    int base = sc[b] - cnt;                         // exclusive prefix
    __syncthreads();
    // ---- local histogram + scan + place ----
    const int* mybuf = bbuf + (size_t)b * cap;
    hist[t] = 0; hist[t + 256] = 0;
    __syncthreads();
    for (int i = t; i < cnt; i += 256)
        atomicAdd(&hist[mybuf[i] >> 17], 1);
    __syncthreads();
    int h0 = hist[2 * t], h1 = hist[2 * t + 1];
    int ps = h0 + h1;
    psum[t] = ps;
    __syncthreads();
    for (int off = 1; off < 256; off <<= 1) {
        int u = (t >= off) ? psum[t - off] : 0;
        __syncthreads();
        psum[t] += u;
        __syncthreads();
    }
    int e0 = psum[t] - ps;                 // exclusive start of pair (2t,2t+1)
    int nodeBase = b * BW;
    cur[2 * t]     = base + e0;
    cur[2 * t + 1] = base + e0 + h0;
    if (nodeBase + 2 * t < n)     rowptr[nodeBase + 2 * t]     = base + e0;
    if (nodeBase + 2 * t + 1 < n) rowptr[nodeBase + 2 * t + 1] = base + e0 + h0;
    __syncthreads();
    for (int i = t; i < cnt; i += 256) {
        int vv = mybuf[i];
        int pos = atomicAdd(&cur[vv >> 17], 1);
        csr[pos] = vv & 0x1FFFF;
    }
}

// -------- MFMA dense: Y = in@Wrel^T (bf16), R = in@Wroot^T + b (bf16) ------
// One wave per 16-node group (2 groups/wave). Consistent k-permutation on
// A and B frags cancels vs HW slot order. C/D: col=lane&15, row=(lane>>4)*4+reg.
// Block 0 also zeroes Y row n (the gather tail's dummy row).
template<bool BF16IN>
__global__ __launch_bounds__(256) void k_xform_mfma(const void* in_,
                                                    const float* __restrict__ Wrel,
                                                    const float* __restrict__ Wroot,
                                                    const float* __restrict__ bias,
                                                    u16* __restrict__ Y,
                                                    u16* R, int n, int ngroups)
{
    if (blockIdx.x == 0 && threadIdx.x < 64)
        Y[(size_t)n * CH + threadIdx.x] = 0;     // zero dummy row

    int lane = threadIdx.x & 63;
    int lr = lane & 15;      // A-row / B-row(=out ch) / D-col
    int g  = lane >> 4;      // k-group

    bf16x8 wf[2][4][2];
    const float* Wm[2] = { Wrel, Wroot };
#pragma unroll
    for (int m = 0; m < 2; ++m)
#pragma unroll
        for (int t = 0; t < 4; ++t)
#pragma unroll
            for (int kt = 0; kt < 2; ++kt) {
                const float* p = Wm[m] + (16 * t + lr) * CH + 32 * kt + 8 * g;
                bf16x8 v;
#pragma unroll
                for (int j = 0; j < 8; ++j) v[j] = (short)f2bf(p[j]);
                wf[m][t][kt] = v;
            }
    float bvt[4];
#pragma unroll
    for (int t = 0; t < 4; ++t) bvt[t] = bias[16 * t + lr];

    int wid = blockIdx.x * 4 + (threadIdx.x >> 6);
#pragma unroll
    for (int gi = 0; gi < 2; ++gi) {
        int grp = wid * 2 + gi;
        if (grp >= ngroups) return;
        int gbase = grp * 16;
        int arow = gbase + lr;
        if (arow >= n) arow = n - 1;

        bf16x8 af[2];
#pragma unroll
        for (int kt = 0; kt < 2; ++kt) {
            if (BF16IN) {
                const u16* hp = (const u16*)in_ + (size_t)arow * CH + kt * 32 + 8 * g;
                af[kt] = *(const bf16x8*)hp;
            } else {
                const float* xp = (const float*)in_ + (size_t)arow * CH + kt * 32 + 8 * g;
                bf16x8 v;
#pragma unroll
                for (int j = 0; j < 8; ++j) v[j] = (short)f2bf(xp[j]);
                af[kt] = v;
            }
        }

        f32x4 z = { 0.f, 0.f, 0.f, 0.f };
        f32x4 aY[4] = { z, z, z, z };
        f32x4 aR[4] = { z, z, z, z };
#pragma unroll
        for (int kt = 0; kt < 2; ++kt)
#pragma unroll
            for (int t = 0; t < 4; ++t) {
                aY[t] = __builtin_amdgcn_mfma_f32_16x16x32_bf16(af[kt], wf[0][t][kt], aY[t], 0, 0, 0);
                aR[t] = __builtin_amdgcn_mfma_f32_16x16x32_bf16(af[kt], wf[1][t][kt], aR[t], 0, 0, 0);
            }

#pragma unroll
        for (int t = 0; t < 4; ++t)
#pragma unroll
            for (int r = 0; r < 4; ++r) {
                int node = gbase + 4 * g + r;
                if (node < n) {
                    Y[(size_t)node * CH + 16 * t + lr] = f2bf(aY[t][r]);
                    R[(size_t)node * CH + 16 * t + lr] = f2bf(aR[t][r] + bvt[t]);
                }
            }
    }
}

// -------- gather v5: R5 main loop + one clamped tail round ------------------
// Whole wave per node; 16 lanes x uint2 = full bf16 row; 4 groups x 4 edges
// per 16-edge granule with scalar broadcast csr loads (R5 shape, proven).
// Tail (<=15 edges): ONE round with invalid slots selecting zero row n
// (L1-hot) -> flat ~2 dependent round trips per node. Chunked-contiguous
// node assignment in both variants (rowptr e1->e0 reuse); RO prefetched.
template<bool POOL>
__global__ __launch_bounds__(256) void k_gather5(const u16* __restrict__ Y,
                                                 const int* __restrict__ rowptr,
                                                 const int* __restrict__ csr,
                                                 u16* RO,
                                                 const int* __restrict__ batch,
                                                 float* __restrict__ sums,
                                                 int n, int chunk)
{
    int lane = threadIdx.x & 63;
    int grp = lane >> 4, sub = lane & 15;
    int wid = blockIdx.x * 4 + (threadIdx.x >> 6);
    int nb = wid * chunk, ne = min(nb + chunk, n);
    if (nb >= n) return;
    float4 run = make_float4(0, 0, 0, 0);
    int gcur = -1;
    int e0 = rowptr[nb];
    for (int node = nb; node < ne; ++node) {
        int e1 = rowptr[node + 1];
        uint2 pr = *(const uint2*)(RO + (size_t)node * CH + sub * 4);
        float4 a0 = make_float4(0, 0, 0, 0), a1 = a0;
        int e = e0;
        for (; e + 16 <= e1; e += 16) {
            int s0 = csr[e + grp],      s1 = csr[e + 4 + grp];
            int s2 = csr[e + 8 + grp],  s3 = csr[e + 12 + grp];
            uint2 p0 = *(const uint2*)(Y + (size_t)s0 * CH + sub * 4);
            uint2 p1 = *(const uint2*)(Y + (size_t)s1 * CH + sub * 4);
            uint2 p2 = *(const uint2*)(Y + (size_t)s2 * CH + sub * 4);
            uint2 p3 = *(const uint2*)(Y + (size_t)s3 * CH + sub * 4);
            bfacc(a0, p0.x, p0.y); bfacc(a1, p1.x, p1.y);
            bfacc(a0, p2.x, p2.y); bfacc(a1, p3.x, p3.y);
        }
        if (e < e1) {   // one clamped round covers the <=15-edge tail
            int s0 = (e + grp      < e1) ? csr[e + grp]      : n;
            int s1 = (e + 4 + grp  < e1) ? csr[e + 4 + grp]  : n;
            int s2 = (e + 8 + grp  < e1) ? csr[e + 8 + grp]  : n;
            int s3 = (e + 12 + grp < e1) ? csr[e + 12 + grp] : n;
            uint2 p0 = *(const uint2*)(Y + (size_t)s0 * CH + sub * 4);
            uint2 p1 = *(const uint2*)(Y + (size_t)s1 * CH + sub * 4);
            uint2 p2 = *(const uint2*)(Y + (size_t)s2 * CH + sub * 4);
            uint2 p3 = *(const uint2*)(Y + (size_t)s3 * CH + sub * 4);
            bfacc(a0, p0.x, p0.y); bfacc(a1, p1.x, p1.y);
            bfacc(a0, p2.x, p2.y); bfacc(a1, p3.x, p3.y);
        }
        e0 = e1;
        f4add(a0, a1);
        a0.x += __shfl_xor(a0.x, 16); a0.y += __shfl_xor(a0.y, 16);
        a0.z += __shfl_xor(a0.z, 16); a0.w += __shfl_xor(a0.w, 16);
        a0.x += __shfl_xor(a0.x, 32); a0.y += __shfl_xor(a0.y, 32);
        a0.z += __shfl_xor(a0.z, 32); a0.w += __shfl_xor(a0.w, 32);
        float4 r = make_float4(0, 0, 0, 0);
        bfacc(r, pr.x, pr.y);
        float4 h;
        h.x = fmaxf(a0.x + r.x, 0.f); h.y = fmaxf(a0.y + r.y, 0.f);
        h.z = fmaxf(a0.z + r.z, 0.f); h.w = fmaxf(a0.w + r.w, 0.f);
        if (!POOL) {
            if (grp == 0) {
                uint2 o;
                o.x = (unsigned)f2bf(h.x) | ((unsigned)f2bf(h.y) << 16);
                o.y = (unsigned)f2bf(h.z) | ((unsigned)f2bf(h.w) << 16);
                *(uint2*)(RO + (size_t)node * CH + sub * 4) = o;
            }
        } else {
            int g = batch[node];
            if (g != gcur) {
                if (gcur >= 0 && grp == 0) {
                    float* s = sums + gcur * CH + sub * 4;
                    atomicAdd(s + 0, run.x); atomicAdd(s + 1, run.y);
                    atomicAdd(s + 2, run.z); atomicAdd(s + 3, run.w);
                }
                run = make_float4(0, 0, 0, 0);
                gcur = g;
            }
            f4add(run, h);
        }
    }
    if (POOL && gcur >= 0 && grp == 0) {
        float* s = sums + gcur * CH + sub * 4;
        atomicAdd(s + 0, run.x); atomicAdd(s + 1, run.y);
        atomicAdd(s + 2, run.z); atomicAdd(s + 3, run.w);
    }
}

// -------- final head --------------------------------------------------------
__global__ void k_final(const float* __restrict__ sums,
                        const int* __restrict__ batch,
                        const float* __restrict__ Wlin,
                        const float* __restrict__ blin,
                        float* __restrict__ out, int n_nodes)
{
    int t = threadIdx.x;
    if (t >= NG * NC) return;
    int g = t / NC, c = t % NC;
    int lo = 0, hi = n_nodes;
    while (lo < hi) { int mid = (lo + hi) >> 1; if (batch[mid] < g) lo = mid + 1; else hi = mid; }
    int lb = lo;
    lo = 0; hi = n_nodes;
    while (lo < hi) { int mid = (lo + hi) >> 1; if (batch[mid] < g + 1) lo = mid + 1; else hi = mid; }
    int cnt = lo - lb;
    float inv = 1.0f / fmaxf((float)cnt, 1.0f);
    float acc = blin[c];
    for (int k = 0; k < CH; ++k)
        acc += sums[g * CH + k] * inv * Wlin[c * CH + k];
    out[g * NC + c] = acc;
}

extern "C" void kernel_launch(void* const* d_in, const int* in_sizes, int n_in,
                              void* d_out, int out_size, void* d_ws, size_t ws_size,
                              hipStream_t stream)
{
    const float* x      = (const float*)d_in[0];
    const int*   ei     = (const int*)d_in[1];
    const int*   batch  = (const int*)d_in[2];
    const float* W1rel  = (const float*)d_in[3];
    const float* W1root = (const float*)d_in[4];
    const float* b1     = (const float*)d_in[5];
    const float* W2rel  = (const float*)d_in[6];
    const float* W2root = (const float*)d_in[7];
    const float* b2     = (const float*)d_in[8];
    const float* Wlin   = (const float*)d_in[9];
    const float* blin   = (const float*)d_in[10];
    float* out = (float*)d_out;

    int n_nodes = in_sizes[0] / CH;
    int n_edges = in_sizes[1] / 2;
    const int* src = ei;
    const int* dst = ei + n_edges;

    int nb  = (n_nodes + BW - 1) >> SHIFT;          // buckets (<=256)
    int cap = n_edges / nb + 2048;                  // per-bucket capacity

    // workspace: Ybf(n+1 rows) | Rbf | rowptr | csr(+16 pad) | bbuf | bcnt | sums
    u16*   Ybf    = (u16*)d_ws;
    u16*   Rbf    = Ybf + (size_t)(n_nodes + 1) * CH;
    int*   rowptr = (int*)(Rbf + (size_t)n_nodes * CH);
    int*   csr    = rowptr + (n_nodes + 1);
    int*   bbuf   = csr + n_edges + 16;             // +16: tail overread pad
    int*   bcnt   = bbuf + (size_t)nb * cap;
    float* sums   = (float*)(bcnt + 256);

    // ---- build CSR (dst -> srcs) via bucketed counting sort ----
    hipMemsetAsync(bcnt, 0, 256 * sizeof(int), stream);
    int b1blocks = (n_edges + EPW - 1) / EPW;
    k_bucket<<<b1blocks, 256, 0, stream>>>(src, dst, bcnt, bbuf, nb, cap, n_edges);
    k_build<<<nb, 256, 0, stream>>>(bbuf, bcnt, rowptr, csr, nb, cap, n_nodes);

    int ngroups16 = (n_nodes + 15) / 16;
    int xblocks = (ngroups16 + 7) / 8;              // 4 waves x 2 groups

    int waves = 2048 * 4;
    int chunk = (n_nodes + waves - 1) / waves;

    // ---- layer 1 ----
    k_xform_mfma<false><<<xblocks, 256, 0, stream>>>(x, W1rel, W1root, b1,
                                                     Ybf, Rbf, n_nodes, ngroups16);
    k_gather5<false><<<2048, 256, 0, stream>>>(Ybf, rowptr, csr, Rbf,
                                               batch, sums, n_nodes, chunk);

    // ---- layer 2 ----
    k_xform_mfma<true><<<xblocks, 256, 0, stream>>>(Rbf, W2rel, W2root, b2,
                                                    Ybf, Rbf, n_nodes, ngroups16);
    hipMemsetAsync(sums, 0, NG * CH * sizeof(float), stream);
    k_gather5<true><<<2048, 256, 0, stream>>>(Ybf, rowptr, csr, Rbf,
                                              batch, sums, n_nodes, chunk);

    // ---- head ----
    k_final<<<1, NG * NC, 0, stream>>>(sums, batch, Wlin, blin, out, n_nodes);
}